// Round 1
// baseline (5242.055 us; speedup 1.0000x reference)
//
#include <hip/hip_runtime.h>
#include <math.h>

// ---- problem constants ----
#define BATCH   16
#define SEQ     96
#define NVARS   862
#define NMARK   4
#define LTOK    866          // NVARS + NMARK
#define MROWS   (BATCH*LTOK) // 13856
#define DM      512
#define DSTATE  16
#define DTRANK  32
#define DFF     512
#define PRED    96
#define EPS_F   1e-5f

// =====================================================================
// Generic fp32 GEMM:  out[m,n] = act( A[row(m),:K] . W[n,:K] + bias[n] ) + res[m,n]
// A row-major (lda), W row-major (N x K, ld = K). rev: A row read reversed
// within each length-LTOK segment. final_mode: write transposed/denormed
// into d_out (B, PRED, NVARS).
// Tile 128x128, BK=8, 256 threads, 8x8 per thread (2x2 quadrants of 4).
// =====================================================================
__global__ __launch_bounds__(256) void gemm_kernel(
    const float* __restrict__ A, int lda,
    const float* __restrict__ W,
    const float* __restrict__ bias,
    const float* __restrict__ res,
    float* __restrict__ out, int ldo,
    int M, int N, int K, int rev, int act,
    int final_mode, const float* __restrict__ fstd, const float* __restrict__ fmean)
{
    __shared__ float As[8][128 + 4];
    __shared__ float Ws[8][128 + 4];
    const int tid = threadIdx.x;
    const int m0 = blockIdx.y * 128, n0 = blockIdx.x * 128;
    const int tm0 = (tid >> 4) * 4;   // 0..60
    const int tn0 = (tid & 15) * 4;   // 0..60

    float acc[8][8];
#pragma unroll
    for (int i = 0; i < 8; ++i)
#pragma unroll
        for (int j = 0; j < 8; ++j) acc[i][j] = 0.f;

    const int lrow = tid >> 1;        // 0..127
    const int lcol = (tid & 1) * 4;   // 0 or 4

    const int gm = m0 + lrow;
    const bool avalid = (gm < M);
    size_t arow_off = 0;
    if (avalid) {
        int rm = gm;
        if (rev) { int b = gm / LTOK; int t = gm - b * LTOK; rm = b * LTOK + (LTOK - 1 - t); }
        arow_off = (size_t)rm * lda;
    }
    const int gn = n0 + lrow;
    const bool wvalid = (gn < N);
    const size_t wrow_off = (size_t)gn * K;

    for (int k0 = 0; k0 < K; k0 += 8) {
        float4 av = make_float4(0.f, 0.f, 0.f, 0.f);
        float4 wv = make_float4(0.f, 0.f, 0.f, 0.f);
        if (avalid) av = *(const float4*)(A + arow_off + k0 + lcol);
        if (wvalid) wv = *(const float4*)(W + wrow_off + k0 + lcol);
        As[lcol + 0][lrow] = av.x; As[lcol + 1][lrow] = av.y;
        As[lcol + 2][lrow] = av.z; As[lcol + 3][lrow] = av.w;
        Ws[lcol + 0][lrow] = wv.x; Ws[lcol + 1][lrow] = wv.y;
        Ws[lcol + 2][lrow] = wv.z; Ws[lcol + 3][lrow] = wv.w;
        __syncthreads();
#pragma unroll
        for (int kk = 0; kk < 8; ++kk) {
            float a[8], b[8];
            *(float4*)&a[0] = *(const float4*)&As[kk][tm0];
            *(float4*)&a[4] = *(const float4*)&As[kk][tm0 + 64];
            *(float4*)&b[0] = *(const float4*)&Ws[kk][tn0];
            *(float4*)&b[4] = *(const float4*)&Ws[kk][tn0 + 64];
#pragma unroll
            for (int i = 0; i < 8; ++i)
#pragma unroll
                for (int j = 0; j < 8; ++j)
                    acc[i][j] = fmaf(a[i], b[j], acc[i][j]);
        }
        __syncthreads();
    }

#pragma unroll
    for (int i = 0; i < 8; ++i) {
        const int gmi = m0 + tm0 + (i < 4 ? i : 60 + i); // quadrant offset +64
        if (gmi >= M) continue;
#pragma unroll
        for (int j = 0; j < 8; ++j) {
            const int gnj = n0 + tn0 + (j < 4 ? j : 60 + j);
            if (gnj >= N) continue;
            float v = acc[i][j];
            if (bias) v += bias[gnj];
            if (act == 1) v = fmaxf(v, 0.f);
            else if (act == 2) v = (v > 20.f) ? v : log1pf(__expf(v)); // softplus
            if (res) v += res[(size_t)gmi * DM + gnj];
            if (!final_mode) {
                out[(size_t)gmi * ldo + gnj] = v;
            } else {
                const int bb = gmi / LTOK, vv = gmi - bb * LTOK;
                if (vv < NVARS) {
                    out[((size_t)bb * PRED + gnj) * NVARS + vv] =
                        v * fstd[bb * NVARS + vv] + fmean[bb * NVARS + vv];
                }
            }
        }
    }
}

// ---- per-(b,var) mean / stdev over SEQ ----
__global__ void stats_kernel(const float* __restrict__ x_enc,
                             float* __restrict__ means, float* __restrict__ stdev)
{
    int i = blockIdx.x * blockDim.x + threadIdx.x;
    if (i >= BATCH * NVARS) return;
    int b = i / NVARS, v = i - b * NVARS;
    const float* p = x_enc + (size_t)b * SEQ * NVARS + v;
    float s = 0.f;
    for (int t = 0; t < SEQ; ++t) s += p[(size_t)t * NVARS];
    float mu = s / (float)SEQ;
    float ss = 0.f;
    for (int t = 0; t < SEQ; ++t) { float d = p[(size_t)t * NVARS] - mu; ss += d * d; }
    means[i] = mu;
    stdev[i] = sqrtf(ss / (float)SEQ + EPS_F);
}

// ---- build token matrix (MROWS x SEQ): normalized vars + marks, transposed ----
__global__ void tok_kernel(const float* __restrict__ x_enc, const float* __restrict__ x_mark,
                           const float* __restrict__ means, const float* __restrict__ stdev,
                           float* __restrict__ tok)
{
    int i = blockIdx.x * blockDim.x + threadIdx.x;
    if (i >= MROWS * SEQ) return;
    int s = i % SEQ;
    int row = i / SEQ;
    int b = row / LTOK, l = row - b * LTOK;
    float val;
    if (l < NVARS) {
        val = (x_enc[((size_t)b * SEQ + s) * NVARS + l] - means[b * NVARS + l])
              / stdev[b * NVARS + l];
    } else {
        val = x_mark[((size_t)b * SEQ + s) * NMARK + (l - NVARS)];
    }
    tok[i] = val;
}

// ---- causal depthwise conv (width 2) + SiLU; xz is (MROWS x 1024), xi = cols [0,512) ----
__global__ void conv_silu_kernel(const float* __restrict__ xz, float* __restrict__ xc,
                                 const float* __restrict__ cW, const float* __restrict__ cb)
{
    int i = blockIdx.x * blockDim.x + threadIdx.x;
    if (i >= MROWS * DM) return;
    int d = i & (DM - 1);
    int row = i >> 9;
    int t = row % LTOK;
    float cur = xz[(size_t)row * 1024 + d];
    float prev = (t == 0) ? 0.f : xz[(size_t)(row - 1) * 1024 + d];
    float v = prev * cW[d * 2 + 0] + cur * cW[d * 2 + 1] + cb[d];
    xc[i] = v / (1.f + __expf(-v)) * 1.f * (v == v ? 1.f : 1.f) * 1.f, // silu
    xc[i] = v * (1.f / (1.f + __expf(-v)));
}

// ---- selective scan: lane = (d,s); 16-lane shuffle reduce; epilogue y*silu(z) ----
__global__ __launch_bounds__(256) void scan_kernel(
    const float* __restrict__ xc, const float* __restrict__ dt,
    const float* __restrict__ dbc, const float* __restrict__ xz,
    const float* __restrict__ A_log, const float* __restrict__ Dp,
    float* __restrict__ ym)
{
    const int s  = threadIdx.x & 15;
    const int dl = threadIdx.x >> 4;           // 0..15
    const int d  = blockIdx.x * 16 + dl;       // 0..511
    const int b  = blockIdx.y;                 // 0..15
    const float Ads = -__expf(A_log[d * DSTATE + s]);
    const float Dd  = Dp[d];
    float h = 0.f;
    const size_t base = (size_t)b * LTOK;
    for (int t = 0; t < LTOK; ++t) {
        const size_t row = base + t;
        const float dtv = dt[row * DM + d];
        const float xcv = xc[row * DM + d];
        const float Bv  = dbc[row * 64 + DTRANK + s];
        const float Cv  = dbc[row * 64 + DTRANK + DSTATE + s];
        const float dA  = __expf(dtv * Ads);
        h = dA * h + (dtv * xcv) * Bv;
        float p = h * Cv;
        p += __shfl_xor(p, 1);
        p += __shfl_xor(p, 2);
        p += __shfl_xor(p, 4);
        p += __shfl_xor(p, 8);
        if (s == 0) {
            const float y = p + xcv * Dd;
            const float z = xz[row * 1024 + DM + d];
            ym[row * DM + d] = y * (z * (1.f / (1.f + __expf(-z))));
        }
    }
}

// ---- LayerNorm over DM=512 per row ----
__global__ __launch_bounds__(256) void ln_kernel(const float* __restrict__ in,
                                                 const float* __restrict__ w,
                                                 const float* __restrict__ bp,
                                                 float* __restrict__ out)
{
    const int row = blockIdx.x;
    const int tid = threadIdx.x;
    const float2 v = *(const float2*)(in + (size_t)row * DM + tid * 2);
    float s  = v.x + v.y;
    float ss = v.x * v.x + v.y * v.y;
    for (int off = 32; off; off >>= 1) {
        s  += __shfl_down(s, off);
        ss += __shfl_down(ss, off);
    }
    __shared__ float sh[10];
    const int wid = tid >> 6, lane = tid & 63;
    if (lane == 0) { sh[wid] = s; sh[4 + wid] = ss; }
    __syncthreads();
    if (tid == 0) {
        float S = sh[0] + sh[1] + sh[2] + sh[3];
        float SS = sh[4] + sh[5] + sh[6] + sh[7];
        float mu = S / (float)DM;
        float var = SS / (float)DM - mu * mu;
        sh[8] = mu; sh[9] = rsqrtf(var + EPS_F);
    }
    __syncthreads();
    const float mu = sh[8], rstd = sh[9];
    const int c = tid * 2;
    float2 o;
    o.x = (v.x - mu) * rstd * w[c]     + bp[c];
    o.y = (v.y - mu) * rstd * w[c + 1] + bp[c + 1];
    *(float2*)(out + (size_t)row * DM + c) = o;
}

// =====================================================================
static inline void launch_gemm(hipStream_t st, const float* A, int lda, const float* W,
                               const float* bias, const float* res, float* out, int ldo,
                               int M, int N, int K, int rev, int act,
                               int fin = 0, const float* fstd = nullptr, const float* fmean = nullptr)
{
    dim3 g((N + 127) / 128, (M + 127) / 128);
    hipLaunchKernelGGL(gemm_kernel, g, dim3(256), 0, st,
                       A, lda, W, bias, res, out, ldo, M, N, K, rev, act, fin, fstd, fmean);
}

extern "C" void kernel_launch(void* const* d_in, const int* in_sizes, int n_in,
                              void* d_out, int out_size, void* d_ws, size_t ws_size,
                              hipStream_t stream)
{
    const float* x_enc   = (const float*)d_in[0];
    const float* x_mark  = (const float*)d_in[1];
    const float* emb_W   = (const float*)d_in[4];
    const float* emb_b   = (const float*)d_in[5];
    // mamba weights: mf = idx 6..14, mr = idx 15..23
    const float* m_in_W[2]    = { (const float*)d_in[6],  (const float*)d_in[15] };
    const float* m_conv_W[2]  = { (const float*)d_in[7],  (const float*)d_in[16] };
    const float* m_conv_b[2]  = { (const float*)d_in[8],  (const float*)d_in[17] };
    const float* m_xproj_W[2] = { (const float*)d_in[9],  (const float*)d_in[18] };
    const float* m_dt_W[2]    = { (const float*)d_in[10], (const float*)d_in[19] };
    const float* m_dt_b[2]    = { (const float*)d_in[11], (const float*)d_in[20] };
    const float* m_A_log[2]   = { (const float*)d_in[12], (const float*)d_in[21] };
    const float* m_D[2]       = { (const float*)d_in[13], (const float*)d_in[22] };
    const float* m_out_W[2]   = { (const float*)d_in[14], (const float*)d_in[23] };
    const float* conv1_W = (const float*)d_in[24];
    const float* conv1_b = (const float*)d_in[25];
    const float* conv2_W = (const float*)d_in[26];
    const float* conv2_b = (const float*)d_in[27];
    const float* ln1_w = (const float*)d_in[28];
    const float* ln1_b = (const float*)d_in[29];
    const float* ln2_w = (const float*)d_in[30];
    const float* ln2_b = (const float*)d_in[31];
    const float* enc_w = (const float*)d_in[32];
    const float* enc_b = (const float*)d_in[33];
    const float* proj_W = (const float*)d_in[34];
    const float* proj_b = (const float*)d_in[35];

    float* ws = (float*)d_ws;
    // ---- workspace layout (floats), all offsets 64-aligned ----
    size_t o = 0;
    float* means = ws + o; o += 13824;              // 16*862 padded
    float* stdev = ws + o; o += 13824;
    float* xbuf  = ws + o; o += (size_t)MROWS * DM;      // current x
    float* accb  = ws + o; o += (size_t)MROWS * DM;      // residual accumulator
    float* xzb   = ws + o; o += (size_t)MROWS * 1024;    // xz; also tok + ffn hidden
    float* xcb   = ws + o; o += (size_t)MROWS * DM;
    float* dtb   = ws + o; o += (size_t)MROWS * DM;
    float* dbcb  = ws + o; o += (size_t)MROWS * 64;
    float* ybuf  = ws + o; o += (size_t)MROWS * DM;      // scan out; also x2
    float* tok   = xzb;          // MROWS x 96, only used before layer 0
    float* hbuf  = xzb;          // ffn hidden, only used after xz dead
    float* x2buf = ybuf;         // LN1 output, only used after y dead

    // 1) normalization stats + token matrix + embedding
    hipLaunchKernelGGL(stats_kernel, dim3((BATCH * NVARS + 255) / 256), dim3(256), 0, stream,
                       x_enc, means, stdev);
    hipLaunchKernelGGL(tok_kernel, dim3((MROWS * SEQ + 255) / 256), dim3(256), 0, stream,
                       x_enc, x_mark, means, stdev, tok);
    launch_gemm(stream, tok, SEQ, emb_W, emb_b, nullptr, xbuf, DM, MROWS, DM, SEQ, 0, 0);

    // 2) encoder layers
    for (int l = 0; l < 2; ++l) {
        for (int dir = 0; dir < 2; ++dir) {   // 0 = fwd (mf), 1 = rev (mr)
            const float* inW  = m_in_W[dir]    + (size_t)l * 2 * DM * DM;
            const float* cW   = m_conv_W[dir]  + (size_t)l * DM * 2;
            const float* cb   = m_conv_b[dir]  + (size_t)l * DM;
            const float* xpW  = m_xproj_W[dir] + (size_t)l * 64 * DM;
            const float* dtW  = m_dt_W[dir]    + (size_t)l * DM * DTRANK;
            const float* dtbias = m_dt_b[dir]  + (size_t)l * DM;
            const float* Alog = m_A_log[dir]   + (size_t)l * DM * DSTATE;
            const float* Dp   = m_D[dir]       + (size_t)l * DM;
            const float* outW = m_out_W[dir]   + (size_t)l * DM * DM;

            // xz = x(rev?) @ in_W.T   (M x 1024)
            launch_gemm(stream, xbuf, DM, inW, nullptr, nullptr, xzb, 1024,
                        MROWS, 2 * DM, DM, dir, 0);
            // xc = silu(causal_conv(xi))
            hipLaunchKernelGGL(conv_silu_kernel, dim3((MROWS * DM + 255) / 256), dim3(256),
                               0, stream, xzb, xcb, cW, cb);
            // dbc = xc @ xproj_W.T   (M x 64)
            launch_gemm(stream, xcb, DM, xpW, nullptr, nullptr, dbcb, 64,
                        MROWS, 64, DM, 0, 0);
            // dt = softplus(dtr @ dt_W.T + dt_b)   (M x 512), dtr = dbc[:, :32]
            launch_gemm(stream, dbcb, 64, dtW, dtbias, nullptr, dtb, DM,
                        MROWS, DM, DTRANK, 0, 2);
            // selective scan (+ xc*D + *silu(z))
            hipLaunchKernelGGL(scan_kernel, dim3(32, 16), dim3(256), 0, stream,
                               xcb, dtb, dbcb, xzb, Alog, Dp, ybuf);
            // acc = (dir==0 ? x : acc) + ym(rev?) @ out_W.T
            launch_gemm(stream, ybuf, DM, outW, nullptr, dir == 0 ? xbuf : accb,
                        accb, DM, MROWS, DM, DM, dir, 0);
        }
        // x2 = LN1(acc)
        hipLaunchKernelGGL(ln_kernel, dim3(MROWS), dim3(256), 0, stream,
                           accb, ln1_w + l * DM, ln1_b + l * DM, x2buf);
        // h = relu(x2 @ conv1_W.T + b1)
        launch_gemm(stream, x2buf, DM, conv1_W + (size_t)l * DFF * DM,
                    conv1_b + l * DFF, nullptr, hbuf, DFF, MROWS, DFF, DM, 0, 1);
        // acc = x2 + h @ conv2_W.T + b2
        launch_gemm(stream, hbuf, DFF, conv2_W + (size_t)l * DM * DFF,
                    conv2_b + l * DM, x2buf, accb, DM, MROWS, DM, DFF, 0, 0);
        // x = LN2(acc)
        hipLaunchKernelGGL(ln_kernel, dim3(MROWS), dim3(256), 0, stream,
                           accb, ln2_w + l * DM, ln2_b + l * DM, xbuf);
    }

    // 3) final norm + projection + de-norm (transposed write into d_out)
    hipLaunchKernelGGL(ln_kernel, dim3(MROWS), dim3(256), 0, stream,
                       xbuf, enc_w, enc_b, x2buf);
    launch_gemm(stream, x2buf, DM, proj_W, proj_b, nullptr, (float*)d_out, 0,
                MROWS, PRED, DM, 0, 0, 1, stdev, means);
}

// Round 2
// 3784.145 us; speedup vs baseline: 1.3853x; 1.3853x over previous
//
#include <hip/hip_runtime.h>
#include <math.h>

// ---- problem constants ----
#define BATCH   16
#define SEQ     96
#define NVARS   862
#define NMARK   4
#define LTOK    866          // NVARS + NMARK
#define MROWS   (BATCH*LTOK) // 13856
#define DM      512
#define DSTATE  16
#define DTRANK  32
#define DFF     512
#define PRED    96
#define EPS_F   1e-5f

// chunked parallel scan
#define CCH     16           // chunks per sequence
#define TCH     55           // steps per chunk (16*55=880 >= 866)

// =====================================================================
// Generic fp32 GEMM:  out[m,n] = act( A[row(m),:K] . W[n,:K] + bias[n] ) + res[m,n]
// Tile 128x128, BK=8, 256 threads, 8x8 per thread (2x2 quadrants of 4).
// =====================================================================
__global__ __launch_bounds__(256) void gemm_kernel(
    const float* __restrict__ A, int lda,
    const float* __restrict__ W,
    const float* __restrict__ bias,
    const float* __restrict__ res,
    float* __restrict__ out, int ldo,
    int M, int N, int K, int rev, int act,
    int final_mode, const float* __restrict__ fstd, const float* __restrict__ fmean)
{
    __shared__ float As[8][128 + 4];
    __shared__ float Ws[8][128 + 4];
    const int tid = threadIdx.x;
    const int m0 = blockIdx.y * 128, n0 = blockIdx.x * 128;
    const int tm0 = (tid >> 4) * 4;   // 0..60
    const int tn0 = (tid & 15) * 4;   // 0..60

    float acc[8][8];
#pragma unroll
    for (int i = 0; i < 8; ++i)
#pragma unroll
        for (int j = 0; j < 8; ++j) acc[i][j] = 0.f;

    const int lrow = tid >> 1;        // 0..127
    const int lcol = (tid & 1) * 4;   // 0 or 4

    const int gm = m0 + lrow;
    const bool avalid = (gm < M);
    size_t arow_off = 0;
    if (avalid) {
        int rm = gm;
        if (rev) { int b = gm / LTOK; int t = gm - b * LTOK; rm = b * LTOK + (LTOK - 1 - t); }
        arow_off = (size_t)rm * lda;
    }
    const int gn = n0 + lrow;
    const bool wvalid = (gn < N);
    const size_t wrow_off = (size_t)gn * K;

    for (int k0 = 0; k0 < K; k0 += 8) {
        float4 av = make_float4(0.f, 0.f, 0.f, 0.f);
        float4 wv = make_float4(0.f, 0.f, 0.f, 0.f);
        if (avalid) av = *(const float4*)(A + arow_off + k0 + lcol);
        if (wvalid) wv = *(const float4*)(W + wrow_off + k0 + lcol);
        As[lcol + 0][lrow] = av.x; As[lcol + 1][lrow] = av.y;
        As[lcol + 2][lrow] = av.z; As[lcol + 3][lrow] = av.w;
        Ws[lcol + 0][lrow] = wv.x; Ws[lcol + 1][lrow] = wv.y;
        Ws[lcol + 2][lrow] = wv.z; Ws[lcol + 3][lrow] = wv.w;
        __syncthreads();
#pragma unroll
        for (int kk = 0; kk < 8; ++kk) {
            float a[8], b[8];
            *(float4*)&a[0] = *(const float4*)&As[kk][tm0];
            *(float4*)&a[4] = *(const float4*)&As[kk][tm0 + 64];
            *(float4*)&b[0] = *(const float4*)&Ws[kk][tn0];
            *(float4*)&b[4] = *(const float4*)&Ws[kk][tn0 + 64];
#pragma unroll
            for (int i = 0; i < 8; ++i)
#pragma unroll
                for (int j = 0; j < 8; ++j)
                    acc[i][j] = fmaf(a[i], b[j], acc[i][j]);
        }
        __syncthreads();
    }

#pragma unroll
    for (int i = 0; i < 8; ++i) {
        const int gmi = m0 + tm0 + (i < 4 ? i : 60 + i); // quadrant offset +64
        if (gmi >= M) continue;
#pragma unroll
        for (int j = 0; j < 8; ++j) {
            const int gnj = n0 + tn0 + (j < 4 ? j : 60 + j);
            if (gnj >= N) continue;
            float v = acc[i][j];
            if (bias) v += bias[gnj];
            if (act == 1) v = fmaxf(v, 0.f);
            else if (act == 2) v = (v > 20.f) ? v : log1pf(__expf(v)); // softplus
            if (res) v += res[(size_t)gmi * DM + gnj];
            if (!final_mode) {
                out[(size_t)gmi * ldo + gnj] = v;
            } else {
                const int bb = gmi / LTOK, vv = gmi - bb * LTOK;
                if (vv < NVARS) {
                    out[((size_t)bb * PRED + gnj) * NVARS + vv] =
                        v * fstd[bb * NVARS + vv] + fmean[bb * NVARS + vv];
                }
            }
        }
    }
}

// ---- per-(b,var) mean / stdev over SEQ ----
__global__ void stats_kernel(const float* __restrict__ x_enc,
                             float* __restrict__ means, float* __restrict__ stdev)
{
    int i = blockIdx.x * blockDim.x + threadIdx.x;
    if (i >= BATCH * NVARS) return;
    int b = i / NVARS, v = i - b * NVARS;
    const float* p = x_enc + (size_t)b * SEQ * NVARS + v;
    float s = 0.f;
    for (int t = 0; t < SEQ; ++t) s += p[(size_t)t * NVARS];
    float mu = s / (float)SEQ;
    float ss = 0.f;
    for (int t = 0; t < SEQ; ++t) { float d = p[(size_t)t * NVARS] - mu; ss += d * d; }
    means[i] = mu;
    stdev[i] = sqrtf(ss / (float)SEQ + EPS_F);
}

// ---- build token matrix (MROWS x SEQ): normalized vars + marks, transposed ----
__global__ void tok_kernel(const float* __restrict__ x_enc, const float* __restrict__ x_mark,
                           const float* __restrict__ means, const float* __restrict__ stdev,
                           float* __restrict__ tok)
{
    int i = blockIdx.x * blockDim.x + threadIdx.x;
    if (i >= MROWS * SEQ) return;
    int s = i % SEQ;
    int row = i / SEQ;
    int b = row / LTOK, l = row - b * LTOK;
    float val;
    if (l < NVARS) {
        val = (x_enc[((size_t)b * SEQ + s) * NVARS + l] - means[b * NVARS + l])
              / stdev[b * NVARS + l];
    } else {
        val = x_mark[((size_t)b * SEQ + s) * NMARK + (l - NVARS)];
    }
    tok[i] = val;
}

// ---- causal depthwise conv (width 2) + SiLU; xz is (MROWS x 1024), xi = cols [0,512) ----
__global__ void conv_silu_kernel(const float* __restrict__ xz, float* __restrict__ xc,
                                 const float* __restrict__ cW, const float* __restrict__ cb)
{
    int i = blockIdx.x * blockDim.x + threadIdx.x;
    if (i >= MROWS * DM) return;
    int d = i & (DM - 1);
    int row = i >> 9;
    int t = row % LTOK;
    float cur = xz[(size_t)row * 1024 + d];
    float prev = (t == 0) ? 0.f : xz[(size_t)(row - 1) * 1024 + d];
    float v = prev * cW[d * 2 + 0] + cur * cW[d * 2 + 1] + cb[d];
    xc[i] = v * (1.f / (1.f + __expf(-v)));   // silu
}

// =====================================================================
// Chunked parallel selective scan (3 passes).
// Thread mapping (pass 1/3): gid = (((b*CCH + c)*DM + d)*16 + s)
//   s = gid & 15, d = (gid>>4)&511, c = (gid>>13)&15, b = gid>>17
// =====================================================================
__global__ __launch_bounds__(256) void scan1_kernel(
    const float* __restrict__ xc, const float* __restrict__ dt,
    const float* __restrict__ dbc, const float* __restrict__ A_log,
    float* __restrict__ aprod, float* __restrict__ hpart)
{
    const int gid = blockIdx.x * 256 + threadIdx.x;
    const int s = gid & 15;
    const int d = (gid >> 4) & (DM - 1);
    const int c = (gid >> 13) & (CCH - 1);
    const int b = gid >> 17;
    const float Ads = -__expf(A_log[d * DSTATE + s]);
    float h = 0.f, ap = 1.f;
    const int t0 = c * TCH;
    const int tend = min(t0 + TCH, LTOK);
    const size_t base = (size_t)b * LTOK;
    for (int t = t0; t < tend; ++t) {
        const size_t row = base + t;
        const float dtv = dt[row * DM + d];
        const float xcv = xc[row * DM + d];
        const float Bv  = dbc[row * 64 + DTRANK + s];
        const float dA  = __expf(dtv * Ads);
        ap *= dA;
        h = dA * h + (dtv * xcv) * Bv;
    }
    aprod[gid] = ap;
    hpart[gid] = h;
}

__global__ __launch_bounds__(256) void scan2_kernel(
    const float* __restrict__ aprod, const float* __restrict__ hpart,
    float* __restrict__ hinit)
{
    const int gid = blockIdx.x * 256 + threadIdx.x;   // (b, d*16+s): 131072
    const int ds = gid & 8191;
    const int b  = gid >> 13;
    float h = 0.f;
    for (int c = 0; c < CCH; ++c) {
        const size_t idx = ((size_t)(b * CCH + c) << 13) + ds;
        const float ap = aprod[idx];
        const float hp = hpart[idx];
        hinit[idx] = h;
        h = hp + ap * h;
    }
}

__global__ __launch_bounds__(256) void scan3_kernel(
    const float* __restrict__ xc, const float* __restrict__ dt,
    const float* __restrict__ dbc, const float* __restrict__ xz,
    const float* __restrict__ A_log, const float* __restrict__ Dp,
    const float* __restrict__ hinit, float* __restrict__ ym)
{
    const int gid = blockIdx.x * 256 + threadIdx.x;
    const int s = gid & 15;
    const int d = (gid >> 4) & (DM - 1);
    const int c = (gid >> 13) & (CCH - 1);
    const int b = gid >> 17;
    const float Ads = -__expf(A_log[d * DSTATE + s]);
    const float Dd  = Dp[d];
    float h = hinit[gid];
    const int t0 = c * TCH;
    const int tend = min(t0 + TCH, LTOK);
    const size_t base = (size_t)b * LTOK;
    for (int t = t0; t < tend; ++t) {
        const size_t row = base + t;
        const float dtv = dt[row * DM + d];
        const float xcv = xc[row * DM + d];
        const float Bv  = dbc[row * 64 + DTRANK + s];
        const float Cv  = dbc[row * 64 + DTRANK + DSTATE + s];
        const float dA  = __expf(dtv * Ads);
        h = dA * h + (dtv * xcv) * Bv;
        float p = h * Cv;
        p += __shfl_xor(p, 1);
        p += __shfl_xor(p, 2);
        p += __shfl_xor(p, 4);
        p += __shfl_xor(p, 8);
        if (s == 0) {
            const float y = p + xcv * Dd;
            const float z = xz[row * 1024 + DM + d];
            ym[row * DM + d] = y * (z * (1.f / (1.f + __expf(-z))));
        }
    }
}

// ---- LayerNorm over DM=512 per row ----
__global__ __launch_bounds__(256) void ln_kernel(const float* __restrict__ in,
                                                 const float* __restrict__ w,
                                                 const float* __restrict__ bp,
                                                 float* __restrict__ out)
{
    const int row = blockIdx.x;
    const int tid = threadIdx.x;
    const float2 v = *(const float2*)(in + (size_t)row * DM + tid * 2);
    float s  = v.x + v.y;
    float ss = v.x * v.x + v.y * v.y;
    for (int off = 32; off; off >>= 1) {
        s  += __shfl_down(s, off);
        ss += __shfl_down(ss, off);
    }
    __shared__ float sh[10];
    const int wid = tid >> 6, lane = tid & 63;
    if (lane == 0) { sh[wid] = s; sh[4 + wid] = ss; }
    __syncthreads();
    if (tid == 0) {
        float S = sh[0] + sh[1] + sh[2] + sh[3];
        float SS = sh[4] + sh[5] + sh[6] + sh[7];
        float mu = S / (float)DM;
        float var = SS / (float)DM - mu * mu;
        sh[8] = mu; sh[9] = rsqrtf(var + EPS_F);
    }
    __syncthreads();
    const float mu = sh[8], rstd = sh[9];
    const int c = tid * 2;
    float2 o;
    o.x = (v.x - mu) * rstd * w[c]     + bp[c];
    o.y = (v.y - mu) * rstd * w[c + 1] + bp[c + 1];
    *(float2*)(out + (size_t)row * DM + c) = o;
}

// =====================================================================
static inline void launch_gemm(hipStream_t st, const float* A, int lda, const float* W,
                               const float* bias, const float* res, float* out, int ldo,
                               int M, int N, int K, int rev, int act,
                               int fin = 0, const float* fstd = nullptr, const float* fmean = nullptr)
{
    dim3 g((N + 127) / 128, (M + 127) / 128);
    hipLaunchKernelGGL(gemm_kernel, g, dim3(256), 0, st,
                       A, lda, W, bias, res, out, ldo, M, N, K, rev, act, fin, fstd, fmean);
}

extern "C" void kernel_launch(void* const* d_in, const int* in_sizes, int n_in,
                              void* d_out, int out_size, void* d_ws, size_t ws_size,
                              hipStream_t stream)
{
    const float* x_enc   = (const float*)d_in[0];
    const float* x_mark  = (const float*)d_in[1];
    const float* emb_W   = (const float*)d_in[4];
    const float* emb_b   = (const float*)d_in[5];
    const float* m_in_W[2]    = { (const float*)d_in[6],  (const float*)d_in[15] };
    const float* m_conv_W[2]  = { (const float*)d_in[7],  (const float*)d_in[16] };
    const float* m_conv_b[2]  = { (const float*)d_in[8],  (const float*)d_in[17] };
    const float* m_xproj_W[2] = { (const float*)d_in[9],  (const float*)d_in[18] };
    const float* m_dt_W[2]    = { (const float*)d_in[10], (const float*)d_in[19] };
    const float* m_dt_b[2]    = { (const float*)d_in[11], (const float*)d_in[20] };
    const float* m_A_log[2]   = { (const float*)d_in[12], (const float*)d_in[21] };
    const float* m_D[2]       = { (const float*)d_in[13], (const float*)d_in[22] };
    const float* m_out_W[2]   = { (const float*)d_in[14], (const float*)d_in[23] };
    const float* conv1_W = (const float*)d_in[24];
    const float* conv1_b = (const float*)d_in[25];
    const float* conv2_W = (const float*)d_in[26];
    const float* conv2_b = (const float*)d_in[27];
    const float* ln1_w = (const float*)d_in[28];
    const float* ln1_b = (const float*)d_in[29];
    const float* ln2_w = (const float*)d_in[30];
    const float* ln2_b = (const float*)d_in[31];
    const float* enc_w = (const float*)d_in[32];
    const float* enc_b = (const float*)d_in[33];
    const float* proj_W = (const float*)d_in[34];
    const float* proj_b = (const float*)d_in[35];

    float* ws = (float*)d_ws;
    size_t o = 0;
    float* means = ws + o; o += 13824;
    float* stdev = ws + o; o += 13824;
    float* xbuf  = ws + o; o += (size_t)MROWS * DM;
    float* accb  = ws + o; o += (size_t)MROWS * DM;
    float* xzb   = ws + o; o += (size_t)MROWS * 1024;
    float* xcb   = ws + o; o += (size_t)MROWS * DM;
    float* dtb   = ws + o; o += (size_t)MROWS * DM;
    float* dbcb  = ws + o; o += (size_t)MROWS * 64;
    float* ybuf  = ws + o; o += (size_t)MROWS * DM;
    const size_t NSUM = (size_t)BATCH * CCH * DM * 16;   // 2,097,152
    float* aprod = ws + o; o += NSUM;
    float* hpart = ws + o; o += NSUM;
    float* hinit = ws + o; o += NSUM;
    float* tok   = xzb;          // MROWS x 96, only used before layer 0
    float* hbuf  = xzb;          // ffn hidden, only used after xz dead
    float* x2buf = ybuf;         // LN1 output, only used after y dead

    // 1) normalization stats + token matrix + embedding
    hipLaunchKernelGGL(stats_kernel, dim3((BATCH * NVARS + 255) / 256), dim3(256), 0, stream,
                       x_enc, means, stdev);
    hipLaunchKernelGGL(tok_kernel, dim3((MROWS * SEQ + 255) / 256), dim3(256), 0, stream,
                       x_enc, x_mark, means, stdev, tok);
    launch_gemm(stream, tok, SEQ, emb_W, emb_b, nullptr, xbuf, DM, MROWS, DM, SEQ, 0, 0);

    // 2) encoder layers
    for (int l = 0; l < 2; ++l) {
        for (int dir = 0; dir < 2; ++dir) {   // 0 = fwd (mf), 1 = rev (mr)
            const float* inW  = m_in_W[dir]    + (size_t)l * 2 * DM * DM;
            const float* cW   = m_conv_W[dir]  + (size_t)l * DM * 2;
            const float* cb   = m_conv_b[dir]  + (size_t)l * DM;
            const float* xpW  = m_xproj_W[dir] + (size_t)l * 64 * DM;
            const float* dtW  = m_dt_W[dir]    + (size_t)l * DM * DTRANK;
            const float* dtbias = m_dt_b[dir]  + (size_t)l * DM;
            const float* Alog = m_A_log[dir]   + (size_t)l * DM * DSTATE;
            const float* Dp   = m_D[dir]       + (size_t)l * DM;
            const float* outW = m_out_W[dir]   + (size_t)l * DM * DM;

            // xz = x(rev?) @ in_W.T   (M x 1024)
            launch_gemm(stream, xbuf, DM, inW, nullptr, nullptr, xzb, 1024,
                        MROWS, 2 * DM, DM, dir, 0);
            // xc = silu(causal_conv(xi))
            hipLaunchKernelGGL(conv_silu_kernel, dim3((MROWS * DM + 255) / 256), dim3(256),
                               0, stream, xzb, xcb, cW, cb);
            // dbc = xc @ xproj_W.T   (M x 64)
            launch_gemm(stream, xcb, DM, xpW, nullptr, nullptr, dbcb, 64,
                        MROWS, 64, DM, 0, 0);
            // dt = softplus(dtr @ dt_W.T + dt_b)   (M x 512)
            launch_gemm(stream, dbcb, 64, dtW, dtbias, nullptr, dtb, DM,
                        MROWS, DM, DTRANK, 0, 2);
            // selective scan: 3-pass chunked parallel scan
            hipLaunchKernelGGL(scan1_kernel, dim3(NSUM / 256), dim3(256), 0, stream,
                               xcb, dtb, dbcb, Alog, aprod, hpart);
            hipLaunchKernelGGL(scan2_kernel, dim3((BATCH * DM * 16) / 256), dim3(256), 0, stream,
                               aprod, hpart, hinit);
            hipLaunchKernelGGL(scan3_kernel, dim3(NSUM / 256), dim3(256), 0, stream,
                               xcb, dtb, dbcb, xzb, Alog, Dp, hinit, ybuf);
            // acc = (dir==0 ? x : acc) + ym(rev?) @ out_W.T
            launch_gemm(stream, ybuf, DM, outW, nullptr, dir == 0 ? xbuf : accb,
                        accb, DM, MROWS, DM, DM, dir, 0);
        }
        // x2 = LN1(acc)
        hipLaunchKernelGGL(ln_kernel, dim3(MROWS), dim3(256), 0, stream,
                           accb, ln1_w + l * DM, ln1_b + l * DM, x2buf);
        // h = relu(x2 @ conv1_W.T + b1)
        launch_gemm(stream, x2buf, DM, conv1_W + (size_t)l * DFF * DM,
                    conv1_b + l * DFF, nullptr, hbuf, DFF, MROWS, DFF, DM, 0, 1);
        // acc = x2 + h @ conv2_W.T + b2
        launch_gemm(stream, hbuf, DFF, conv2_W + (size_t)l * DM * DFF,
                    conv2_b + l * DM, x2buf, accb, DM, MROWS, DM, DFF, 0, 0);
        // x = LN2(acc)
        hipLaunchKernelGGL(ln_kernel, dim3(MROWS), dim3(256), 0, stream,
                           accb, ln2_w + l * DM, ln2_b + l * DM, xbuf);
    }

    // 3) final norm + projection + de-norm (transposed write into d_out)
    hipLaunchKernelGGL(ln_kernel, dim3(MROWS), dim3(256), 0, stream,
                       xbuf, enc_w, enc_b, x2buf);
    launch_gemm(stream, x2buf, DM, proj_W, proj_b, nullptr, (float*)d_out, 0,
                MROWS, PRED, DM, 0, 0, 1, stdev, means);
}

// Round 3
// 2510.049 us; speedup vs baseline: 2.0884x; 1.5076x over previous
//
#include <hip/hip_runtime.h>
#include <math.h>

// ---- problem constants ----
#define BATCH   16
#define SEQ     96
#define NVARS   862
#define NMARK   4
#define LTOK    866          // NVARS + NMARK
#define MROWS   (BATCH*LTOK) // 13856
#define DM      512
#define DSTATE  16
#define DTRANK  32
#define DFF     512
#define PRED    96
#define EPS_F   1e-5f

// chunked parallel scan
#define CCH     16           // chunks per sequence
#define TCH     55           // steps per chunk (16*55=880 >= 866)

typedef __attribute__((ext_vector_type(4))) float f32x4;
typedef __attribute__((ext_vector_type(8))) short bf16x8;  // 8 bf16 in 4 VGPRs

#define LDSK 40   // LDS row stride in bf16 elems (32 + 8 pad -> <=2-way bank alias)

__device__ __forceinline__ short f2bf(float f) {
    unsigned u = __builtin_bit_cast(unsigned, f);
    u += 0x7fffu + ((u >> 16) & 1u);          // round-to-nearest-even
    return (short)(u >> 16);
}

// =====================================================================
// bf16-MFMA GEMM, fp32 in/out:
//   out[m,n] = act( A[row(m),:K] . W[n,:K] + bias[n] ) + res[m,n]
// A row-major (lda) fp32, W row-major (N x K) fp32; both converted to bf16
// during LDS staging; MFMA accumulates fp32. Tile 128x128, BK=32,
// 256 thr = 4 waves (2x2), each wave 64x64 via 4x4 frags of 16x16x32.
// rev: A rows reversed within each LTOK segment.
// final_mode: transposed/denormed write into d_out (B, PRED, NVARS).
// K must be a multiple of 32 (all call sites: 512/96/32).
// =====================================================================
__global__ __launch_bounds__(256) void gemm_mfma(
    const float* __restrict__ A, int lda,
    const float* __restrict__ W,
    const float* __restrict__ bias,
    const float* __restrict__ res,
    float* __restrict__ out, int ldo,
    int M, int N, int K, int rev, int act,
    int final_mode, const float* __restrict__ fstd, const float* __restrict__ fmean)
{
    __shared__ short Als[128 * LDSK];
    __shared__ short Bls[128 * LDSK];
    const int tid  = threadIdx.x;
    const int lane = tid & 63;
    const int wid  = tid >> 6;
    const int wm   = wid >> 1;        // wave row (0..1)
    const int wn   = wid & 1;         // wave col (0..1)
    const int fr   = lane & 15;       // frag row (A) / col (B)
    const int g    = lane >> 4;       // k-group 0..3
    const int m0 = blockIdx.y * 128, n0 = blockIdx.x * 128;

    // staging slots: slot = tid + q*256; row = slot>>3 (0..127), kg = slot&7
    int    rowq[4], kgq[4];
    size_t aoff[4], woff[4];
    bool   aval[4], wval[4];
#pragma unroll
    for (int q = 0; q < 4; ++q) {
        const int slot = tid + q * 256;
        const int row = slot >> 3, kg = slot & 7;
        rowq[q] = row; kgq[q] = kg;
        const int gm = m0 + row;
        aval[q] = (gm < M);
        int rm = gm;
        if (rev && aval[q]) { int b = gm / LTOK; int t = gm - b * LTOK; rm = b * LTOK + (LTOK - 1 - t); }
        aoff[q] = (size_t)rm * lda + kg * 4;
        const int gn = n0 + row;
        wval[q] = (gn < N);
        woff[q] = (size_t)gn * K + kg * 4;
    }

    f32x4 acc[4][4];
#pragma unroll
    for (int i = 0; i < 4; ++i)
#pragma unroll
        for (int j = 0; j < 4; ++j) { f32x4 z = {0.f, 0.f, 0.f, 0.f}; acc[i][j] = z; }

    for (int k0 = 0; k0 < K; k0 += 32) {
        float4 avq[4], wvq[4];
        const float4 f0 = make_float4(0.f, 0.f, 0.f, 0.f);
#pragma unroll
        for (int q = 0; q < 4; ++q) {
            avq[q] = aval[q] ? *(const float4*)(A + aoff[q] + k0) : f0;
            wvq[q] = wval[q] ? *(const float4*)(W + woff[q] + k0) : f0;
        }
        __syncthreads();   // previous iteration's LDS reads complete
#pragma unroll
        for (int q = 0; q < 4; ++q) {
            short4 sa, sw;
            sa.x = f2bf(avq[q].x); sa.y = f2bf(avq[q].y);
            sa.z = f2bf(avq[q].z); sa.w = f2bf(avq[q].w);
            sw.x = f2bf(wvq[q].x); sw.y = f2bf(wvq[q].y);
            sw.z = f2bf(wvq[q].z); sw.w = f2bf(wvq[q].w);
            *(short4*)&Als[rowq[q] * LDSK + kgq[q] * 4] = sa;
            *(short4*)&Bls[rowq[q] * LDSK + kgq[q] * 4] = sw;
        }
        __syncthreads();

        bf16x8 a4[4], b4[4];
#pragma unroll
        for (int i = 0; i < 4; ++i) {
            a4[i] = *(const bf16x8*)&Als[(wm * 64 + i * 16 + fr) * LDSK + g * 8];
            b4[i] = *(const bf16x8*)&Bls[(wn * 64 + i * 16 + fr) * LDSK + g * 8];
        }
#pragma unroll
        for (int mi = 0; mi < 4; ++mi)
#pragma unroll
            for (int ni = 0; ni < 4; ++ni)
                acc[mi][ni] = __builtin_amdgcn_mfma_f32_16x16x32_bf16(
                    a4[mi], b4[ni], acc[mi][ni], 0, 0, 0);
    }

    // epilogue: C/D layout col=lane&15, row=(lane>>4)*4+j   [m89-verified]
#pragma unroll
    for (int mi = 0; mi < 4; ++mi) {
#pragma unroll
        for (int ni = 0; ni < 4; ++ni) {
            const int gn = n0 + wn * 64 + ni * 16 + fr;
            if (gn >= N) continue;
#pragma unroll
            for (int j = 0; j < 4; ++j) {
                const int gm = m0 + wm * 64 + mi * 16 + g * 4 + j;
                if (gm >= M) continue;
                float v = acc[mi][ni][j];
                if (bias) v += bias[gn];
                if (act == 1) v = fmaxf(v, 0.f);
                else if (act == 2) v = (v > 20.f) ? v : log1pf(__expf(v)); // softplus
                if (res) v += res[(size_t)gm * DM + gn];
                if (!final_mode) {
                    out[(size_t)gm * ldo + gn] = v;
                } else {
                    const int bb = gm / LTOK, vv = gm - bb * LTOK;
                    if (vv < NVARS) {
                        out[((size_t)bb * PRED + gn) * NVARS + vv] =
                            v * fstd[bb * NVARS + vv] + fmean[bb * NVARS + vv];
                    }
                }
            }
        }
    }
}

// ---- per-(b,var) mean / stdev over SEQ ----
__global__ void stats_kernel(const float* __restrict__ x_enc,
                             float* __restrict__ means, float* __restrict__ stdev)
{
    int i = blockIdx.x * blockDim.x + threadIdx.x;
    if (i >= BATCH * NVARS) return;
    int b = i / NVARS, v = i - b * NVARS;
    const float* p = x_enc + (size_t)b * SEQ * NVARS + v;
    float s = 0.f;
    for (int t = 0; t < SEQ; ++t) s += p[(size_t)t * NVARS];
    float mu = s / (float)SEQ;
    float ss = 0.f;
    for (int t = 0; t < SEQ; ++t) { float d = p[(size_t)t * NVARS] - mu; ss += d * d; }
    means[i] = mu;
    stdev[i] = sqrtf(ss / (float)SEQ + EPS_F);
}

// ---- build token matrix (MROWS x SEQ): normalized vars + marks, transposed ----
__global__ void tok_kernel(const float* __restrict__ x_enc, const float* __restrict__ x_mark,
                           const float* __restrict__ means, const float* __restrict__ stdev,
                           float* __restrict__ tok)
{
    int i = blockIdx.x * blockDim.x + threadIdx.x;
    if (i >= MROWS * SEQ) return;
    int s = i % SEQ;
    int row = i / SEQ;
    int b = row / LTOK, l = row - b * LTOK;
    float val;
    if (l < NVARS) {
        val = (x_enc[((size_t)b * SEQ + s) * NVARS + l] - means[b * NVARS + l])
              / stdev[b * NVARS + l];
    } else {
        val = x_mark[((size_t)b * SEQ + s) * NMARK + (l - NVARS)];
    }
    tok[i] = val;
}

// ---- causal depthwise conv (width 2) + SiLU; xz is (MROWS x 1024), xi = cols [0,512) ----
__global__ void conv_silu_kernel(const float* __restrict__ xz, float* __restrict__ xc,
                                 const float* __restrict__ cW, const float* __restrict__ cb)
{
    int i = blockIdx.x * blockDim.x + threadIdx.x;
    if (i >= MROWS * DM) return;
    int d = i & (DM - 1);
    int row = i >> 9;
    int t = row % LTOK;
    float cur = xz[(size_t)row * 1024 + d];
    float prev = (t == 0) ? 0.f : xz[(size_t)(row - 1) * 1024 + d];
    float v = prev * cW[d * 2 + 0] + cur * cW[d * 2 + 1] + cb[d];
    xc[i] = v * (1.f / (1.f + __expf(-v)));   // silu
}

// =====================================================================
// Chunked parallel selective scan (3 passes).
// Thread mapping (pass 1/3): gid = (((b*CCH + c)*DM + d)*16 + s)
// =====================================================================
__global__ __launch_bounds__(256) void scan1_kernel(
    const float* __restrict__ xc, const float* __restrict__ dt,
    const float* __restrict__ dbc, const float* __restrict__ A_log,
    float* __restrict__ aprod, float* __restrict__ hpart)
{
    const int gid = blockIdx.x * 256 + threadIdx.x;
    const int s = gid & 15;
    const int d = (gid >> 4) & (DM - 1);
    const int c = (gid >> 13) & (CCH - 1);
    const int b = gid >> 17;
    const float Ads = -__expf(A_log[d * DSTATE + s]);
    float h = 0.f, ap = 1.f;
    const int t0 = c * TCH;
    const int tend = min(t0 + TCH, LTOK);
    const size_t base = (size_t)b * LTOK;
    for (int t = t0; t < tend; ++t) {
        const size_t row = base + t;
        const float dtv = dt[row * DM + d];
        const float xcv = xc[row * DM + d];
        const float Bv  = dbc[row * 64 + DTRANK + s];
        const float dA  = __expf(dtv * Ads);
        ap *= dA;
        h = dA * h + (dtv * xcv) * Bv;
    }
    aprod[gid] = ap;
    hpart[gid] = h;
}

__global__ __launch_bounds__(256) void scan2_kernel(
    const float* __restrict__ aprod, const float* __restrict__ hpart,
    float* __restrict__ hinit)
{
    const int gid = blockIdx.x * 256 + threadIdx.x;   // (b, d*16+s): 131072
    const int ds = gid & 8191;
    const int b  = gid >> 13;
    float h = 0.f;
    for (int c = 0; c < CCH; ++c) {
        const size_t idx = ((size_t)(b * CCH + c) << 13) + ds;
        const float ap = aprod[idx];
        const float hp = hpart[idx];
        hinit[idx] = h;
        h = hp + ap * h;
    }
}

__global__ __launch_bounds__(256) void scan3_kernel(
    const float* __restrict__ xc, const float* __restrict__ dt,
    const float* __restrict__ dbc, const float* __restrict__ xz,
    const float* __restrict__ A_log, const float* __restrict__ Dp,
    const float* __restrict__ hinit, float* __restrict__ ym)
{
    const int gid = blockIdx.x * 256 + threadIdx.x;
    const int s = gid & 15;
    const int d = (gid >> 4) & (DM - 1);
    const int c = (gid >> 13) & (CCH - 1);
    const int b = gid >> 17;
    const float Ads = -__expf(A_log[d * DSTATE + s]);
    const float Dd  = Dp[d];
    float h = hinit[gid];
    const int t0 = c * TCH;
    const int tend = min(t0 + TCH, LTOK);
    const size_t base = (size_t)b * LTOK;
    for (int t = t0; t < tend; ++t) {
        const size_t row = base + t;
        const float dtv = dt[row * DM + d];
        const float xcv = xc[row * DM + d];
        const float Bv  = dbc[row * 64 + DTRANK + s];
        const float Cv  = dbc[row * 64 + DTRANK + DSTATE + s];
        const float dA  = __expf(dtv * Ads);
        h = dA * h + (dtv * xcv) * Bv;
        float p = h * Cv;
        p += __shfl_xor(p, 1);
        p += __shfl_xor(p, 2);
        p += __shfl_xor(p, 4);
        p += __shfl_xor(p, 8);
        if (s == 0) {
            const float y = p + xcv * Dd;
            const float z = xz[row * 1024 + DM + d];
            ym[row * DM + d] = y * (z * (1.f / (1.f + __expf(-z))));
        }
    }
}

// ---- LayerNorm over DM=512 per row ----
__global__ __launch_bounds__(256) void ln_kernel(const float* __restrict__ in,
                                                 const float* __restrict__ w,
                                                 const float* __restrict__ bp,
                                                 float* __restrict__ out)
{
    const int row = blockIdx.x;
    const int tid = threadIdx.x;
    const float2 v = *(const float2*)(in + (size_t)row * DM + tid * 2);
    float s  = v.x + v.y;
    float ss = v.x * v.x + v.y * v.y;
    for (int off = 32; off; off >>= 1) {
        s  += __shfl_down(s, off);
        ss += __shfl_down(ss, off);
    }
    __shared__ float sh[10];
    const int wid = tid >> 6, lane = tid & 63;
    if (lane == 0) { sh[wid] = s; sh[4 + wid] = ss; }
    __syncthreads();
    if (tid == 0) {
        float S = sh[0] + sh[1] + sh[2] + sh[3];
        float SS = sh[4] + sh[5] + sh[6] + sh[7];
        float mu = S / (float)DM;
        float var = SS / (float)DM - mu * mu;
        sh[8] = mu; sh[9] = rsqrtf(var + EPS_F);
    }
    __syncthreads();
    const float mu = sh[8], rstd = sh[9];
    const int c = tid * 2;
    float2 o;
    o.x = (v.x - mu) * rstd * w[c]     + bp[c];
    o.y = (v.y - mu) * rstd * w[c + 1] + bp[c + 1];
    *(float2*)(out + (size_t)row * DM + c) = o;
}

// =====================================================================
static inline void launch_gemm(hipStream_t st, const float* A, int lda, const float* W,
                               const float* bias, const float* res, float* out, int ldo,
                               int M, int N, int K, int rev, int act,
                               int fin = 0, const float* fstd = nullptr, const float* fmean = nullptr)
{
    dim3 g((N + 127) / 128, (M + 127) / 128);
    hipLaunchKernelGGL(gemm_mfma, g, dim3(256), 0, st,
                       A, lda, W, bias, res, out, ldo, M, N, K, rev, act, fin, fstd, fmean);
}

extern "C" void kernel_launch(void* const* d_in, const int* in_sizes, int n_in,
                              void* d_out, int out_size, void* d_ws, size_t ws_size,
                              hipStream_t stream)
{
    const float* x_enc   = (const float*)d_in[0];
    const float* x_mark  = (const float*)d_in[1];
    const float* emb_W   = (const float*)d_in[4];
    const float* emb_b   = (const float*)d_in[5];
    const float* m_in_W[2]    = { (const float*)d_in[6],  (const float*)d_in[15] };
    const float* m_conv_W[2]  = { (const float*)d_in[7],  (const float*)d_in[16] };
    const float* m_conv_b[2]  = { (const float*)d_in[8],  (const float*)d_in[17] };
    const float* m_xproj_W[2] = { (const float*)d_in[9],  (const float*)d_in[18] };
    const float* m_dt_W[2]    = { (const float*)d_in[10], (const float*)d_in[19] };
    const float* m_dt_b[2]    = { (const float*)d_in[11], (const float*)d_in[20] };
    const float* m_A_log[2]   = { (const float*)d_in[12], (const float*)d_in[21] };
    const float* m_D[2]       = { (const float*)d_in[13], (const float*)d_in[22] };
    const float* m_out_W[2]   = { (const float*)d_in[14], (const float*)d_in[23] };
    const float* conv1_W = (const float*)d_in[24];
    const float* conv1_b = (const float*)d_in[25];
    const float* conv2_W = (const float*)d_in[26];
    const float* conv2_b = (const float*)d_in[27];
    const float* ln1_w = (const float*)d_in[28];
    const float* ln1_b = (const float*)d_in[29];
    const float* ln2_w = (const float*)d_in[30];
    const float* ln2_b = (const float*)d_in[31];
    const float* enc_w = (const float*)d_in[32];
    const float* enc_b = (const float*)d_in[33];
    const float* proj_W = (const float*)d_in[34];
    const float* proj_b = (const float*)d_in[35];

    float* ws = (float*)d_ws;
    size_t o = 0;
    float* means = ws + o; o += 13824;
    float* stdev = ws + o; o += 13824;
    float* xbuf  = ws + o; o += (size_t)MROWS * DM;
    float* accb  = ws + o; o += (size_t)MROWS * DM;
    float* xzb   = ws + o; o += (size_t)MROWS * 1024;
    float* xcb   = ws + o; o += (size_t)MROWS * DM;
    float* dtb   = ws + o; o += (size_t)MROWS * DM;
    float* dbcb  = ws + o; o += (size_t)MROWS * 64;
    float* ybuf  = ws + o; o += (size_t)MROWS * DM;
    const size_t NSUM = (size_t)BATCH * CCH * DM * 16;   // 2,097,152
    float* aprod = ws + o; o += NSUM;
    float* hpart = ws + o; o += NSUM;
    float* hinit = ws + o; o += NSUM;
    float* tok   = xzb;          // MROWS x 96, only used before layer 0
    float* hbuf  = xzb;          // ffn hidden, only used after xz dead
    float* x2buf = ybuf;         // LN1 output, only used after y dead

    // 1) normalization stats + token matrix + embedding
    hipLaunchKernelGGL(stats_kernel, dim3((BATCH * NVARS + 255) / 256), dim3(256), 0, stream,
                       x_enc, means, stdev);
    hipLaunchKernelGGL(tok_kernel, dim3((MROWS * SEQ + 255) / 256), dim3(256), 0, stream,
                       x_enc, x_mark, means, stdev, tok);
    launch_gemm(stream, tok, SEQ, emb_W, emb_b, nullptr, xbuf, DM, MROWS, DM, SEQ, 0, 0);

    // 2) encoder layers
    for (int l = 0; l < 2; ++l) {
        for (int dir = 0; dir < 2; ++dir) {   // 0 = fwd (mf), 1 = rev (mr)
            const float* inW  = m_in_W[dir]    + (size_t)l * 2 * DM * DM;
            const float* cW   = m_conv_W[dir]  + (size_t)l * DM * 2;
            const float* cb   = m_conv_b[dir]  + (size_t)l * DM;
            const float* xpW  = m_xproj_W[dir] + (size_t)l * 64 * DM;
            const float* dtW  = m_dt_W[dir]    + (size_t)l * DM * DTRANK;
            const float* dtbias = m_dt_b[dir]  + (size_t)l * DM;
            const float* Alog = m_A_log[dir]   + (size_t)l * DM * DSTATE;
            const float* Dp   = m_D[dir]       + (size_t)l * DM;
            const float* outW = m_out_W[dir]   + (size_t)l * DM * DM;

            // xz = x(rev?) @ in_W.T   (M x 1024)
            launch_gemm(stream, xbuf, DM, inW, nullptr, nullptr, xzb, 1024,
                        MROWS, 2 * DM, DM, dir, 0);
            // xc = silu(causal_conv(xi))
            hipLaunchKernelGGL(conv_silu_kernel, dim3((MROWS * DM + 255) / 256), dim3(256),
                               0, stream, xzb, xcb, cW, cb);
            // dbc = xc @ xproj_W.T   (M x 64)
            launch_gemm(stream, xcb, DM, xpW, nullptr, nullptr, dbcb, 64,
                        MROWS, 64, DM, 0, 0);
            // dt = softplus(dtr @ dt_W.T + dt_b)   (M x 512)
            launch_gemm(stream, dbcb, 64, dtW, dtbias, nullptr, dtb, DM,
                        MROWS, DM, DTRANK, 0, 2);
            // selective scan: 3-pass chunked parallel scan
            hipLaunchKernelGGL(scan1_kernel, dim3(NSUM / 256), dim3(256), 0, stream,
                               xcb, dtb, dbcb, Alog, aprod, hpart);
            hipLaunchKernelGGL(scan2_kernel, dim3((BATCH * DM * 16) / 256), dim3(256), 0, stream,
                               aprod, hpart, hinit);
            hipLaunchKernelGGL(scan3_kernel, dim3(NSUM / 256), dim3(256), 0, stream,
                               xcb, dtb, dbcb, xzb, Alog, Dp, hinit, ybuf);
            // acc = (dir==0 ? x : acc) + ym(rev?) @ out_W.T
            launch_gemm(stream, ybuf, DM, outW, nullptr, dir == 0 ? xbuf : accb,
                        accb, DM, MROWS, DM, DM, dir, 0);
        }
        // x2 = LN1(acc)
        hipLaunchKernelGGL(ln_kernel, dim3(MROWS), dim3(256), 0, stream,
                           accb, ln1_w + l * DM, ln1_b + l * DM, x2buf);
        // h = relu(x2 @ conv1_W.T + b1)
        launch_gemm(stream, x2buf, DM, conv1_W + (size_t)l * DFF * DM,
                    conv1_b + l * DFF, nullptr, hbuf, DFF, MROWS, DFF, DM, 0, 1);
        // acc = x2 + h @ conv2_W.T + b2
        launch_gemm(stream, hbuf, DFF, conv2_W + (size_t)l * DM * DFF,
                    conv2_b + l * DM, x2buf, accb, DM, MROWS, DM, DFF, 0, 0);
        // x = LN2(acc)
        hipLaunchKernelGGL(ln_kernel, dim3(MROWS), dim3(256), 0, stream,
                           accb, ln2_w + l * DM, ln2_b + l * DM, xbuf);
    }

    // 3) final norm + projection + de-norm (transposed write into d_out)
    hipLaunchKernelGGL(ln_kernel, dim3(MROWS), dim3(256), 0, stream,
                       xbuf, enc_w, enc_b, x2buf);
    launch_gemm(stream, x2buf, DM, proj_W, proj_b, nullptr, (float*)d_out, 0,
                MROWS, PRED, DM, 0, 0, 1, stdev, means);
}

// Round 4
// 1784.671 us; speedup vs baseline: 2.9373x; 1.4064x over previous
//
#include <hip/hip_runtime.h>
#include <math.h>

// ---- problem constants ----
#define BATCH   16
#define SEQ     96
#define NVARS   862
#define NMARK   4
#define LTOK    866          // NVARS + NMARK
#define MROWS   (BATCH*LTOK) // 13856
#define DM      512
#define DSTATE  16
#define DTRANK  32
#define DFF     512
#define PRED    96
#define EPS_F   1e-5f

// chunked parallel scan
#define CCH     32           // chunks per sequence
#define TCH     28           // steps per chunk (32*28=896 >= 866)

typedef __attribute__((ext_vector_type(4))) float f32x4;
typedef __attribute__((ext_vector_type(8))) short bf16x8;  // 8 bf16 in 4 VGPRs

#define LDSK 40   // LDS row stride in bf16 elems (32 + 8 pad -> <=2-way bank alias)

__device__ __forceinline__ short f2bf(float f) {
    unsigned u = __builtin_bit_cast(unsigned, f);
    u += 0x7fffu + ((u >> 16) & 1u);          // round-to-nearest-even
    return (short)(u >> 16);
}

// =====================================================================
// bf16-MFMA GEMM, fp32 in/out (unchanged from round 3; see comments there)
// =====================================================================
__global__ __launch_bounds__(256) void gemm_mfma(
    const float* __restrict__ A, int lda,
    const float* __restrict__ W,
    const float* __restrict__ bias,
    const float* __restrict__ res,
    float* __restrict__ out, int ldo,
    int M, int N, int K, int rev, int act,
    int final_mode, const float* __restrict__ fstd, const float* __restrict__ fmean)
{
    __shared__ short Als[128 * LDSK];
    __shared__ short Bls[128 * LDSK];
    const int tid  = threadIdx.x;
    const int lane = tid & 63;
    const int wid  = tid >> 6;
    const int wm   = wid >> 1;        // wave row (0..1)
    const int wn   = wid & 1;         // wave col (0..1)
    const int fr   = lane & 15;       // frag row (A) / col (B)
    const int g    = lane >> 4;       // k-group 0..3
    const int m0 = blockIdx.y * 128, n0 = blockIdx.x * 128;

    int    rowq[4], kgq[4];
    size_t aoff[4], woff[4];
    bool   aval[4], wval[4];
#pragma unroll
    for (int q = 0; q < 4; ++q) {
        const int slot = tid + q * 256;
        const int row = slot >> 3, kg = slot & 7;
        rowq[q] = row; kgq[q] = kg;
        const int gm = m0 + row;
        aval[q] = (gm < M);
        int rm = gm;
        if (rev && aval[q]) { int b = gm / LTOK; int t = gm - b * LTOK; rm = b * LTOK + (LTOK - 1 - t); }
        aoff[q] = (size_t)rm * lda + kg * 4;
        const int gn = n0 + row;
        wval[q] = (gn < N);
        woff[q] = (size_t)gn * K + kg * 4;
    }

    f32x4 acc[4][4];
#pragma unroll
    for (int i = 0; i < 4; ++i)
#pragma unroll
        for (int j = 0; j < 4; ++j) { f32x4 z = {0.f, 0.f, 0.f, 0.f}; acc[i][j] = z; }

    for (int k0 = 0; k0 < K; k0 += 32) {
        float4 avq[4], wvq[4];
        const float4 f0 = make_float4(0.f, 0.f, 0.f, 0.f);
#pragma unroll
        for (int q = 0; q < 4; ++q) {
            avq[q] = aval[q] ? *(const float4*)(A + aoff[q] + k0) : f0;
            wvq[q] = wval[q] ? *(const float4*)(W + woff[q] + k0) : f0;
        }
        __syncthreads();   // previous iteration's LDS reads complete
#pragma unroll
        for (int q = 0; q < 4; ++q) {
            short4 sa, sw;
            sa.x = f2bf(avq[q].x); sa.y = f2bf(avq[q].y);
            sa.z = f2bf(avq[q].z); sa.w = f2bf(avq[q].w);
            sw.x = f2bf(wvq[q].x); sw.y = f2bf(wvq[q].y);
            sw.z = f2bf(wvq[q].z); sw.w = f2bf(wvq[q].w);
            *(short4*)&Als[rowq[q] * LDSK + kgq[q] * 4] = sa;
            *(short4*)&Bls[rowq[q] * LDSK + kgq[q] * 4] = sw;
        }
        __syncthreads();

        bf16x8 a4[4], b4[4];
#pragma unroll
        for (int i = 0; i < 4; ++i) {
            a4[i] = *(const bf16x8*)&Als[(wm * 64 + i * 16 + fr) * LDSK + g * 8];
            b4[i] = *(const bf16x8*)&Bls[(wn * 64 + i * 16 + fr) * LDSK + g * 8];
        }
#pragma unroll
        for (int mi = 0; mi < 4; ++mi)
#pragma unroll
            for (int ni = 0; ni < 4; ++ni)
                acc[mi][ni] = __builtin_amdgcn_mfma_f32_16x16x32_bf16(
                    a4[mi], b4[ni], acc[mi][ni], 0, 0, 0);
    }

    // epilogue: C/D layout col=lane&15, row=(lane>>4)*4+j   [m89-verified]
#pragma unroll
    for (int mi = 0; mi < 4; ++mi) {
#pragma unroll
        for (int ni = 0; ni < 4; ++ni) {
            const int gn = n0 + wn * 64 + ni * 16 + fr;
            if (gn >= N) continue;
#pragma unroll
            for (int j = 0; j < 4; ++j) {
                const int gm = m0 + wm * 64 + mi * 16 + g * 4 + j;
                if (gm >= M) continue;
                float v = acc[mi][ni][j];
                if (bias) v += bias[gn];
                if (act == 1) v = fmaxf(v, 0.f);
                else if (act == 2) v = (v > 20.f) ? v : log1pf(__expf(v)); // softplus
                if (res) v += res[(size_t)gm * DM + gn];
                if (!final_mode) {
                    out[(size_t)gm * ldo + gn] = v;
                } else {
                    const int bb = gm / LTOK, vv = gm - bb * LTOK;
                    if (vv < NVARS) {
                        out[((size_t)bb * PRED + gn) * NVARS + vv] =
                            v * fstd[bb * NVARS + vv] + fmean[bb * NVARS + vv];
                    }
                }
            }
        }
    }
}

// ---- per-(b,var) mean / stdev over SEQ ----
__global__ void stats_kernel(const float* __restrict__ x_enc,
                             float* __restrict__ means, float* __restrict__ stdev)
{
    int i = blockIdx.x * blockDim.x + threadIdx.x;
    if (i >= BATCH * NVARS) return;
    int b = i / NVARS, v = i - b * NVARS;
    const float* p = x_enc + (size_t)b * SEQ * NVARS + v;
    float s = 0.f;
    for (int t = 0; t < SEQ; ++t) s += p[(size_t)t * NVARS];
    float mu = s / (float)SEQ;
    float ss = 0.f;
    for (int t = 0; t < SEQ; ++t) { float d = p[(size_t)t * NVARS] - mu; ss += d * d; }
    means[i] = mu;
    stdev[i] = sqrtf(ss / (float)SEQ + EPS_F);
}

// ---- build token matrix (MROWS x SEQ): normalized vars + marks, transposed ----
__global__ void tok_kernel(const float* __restrict__ x_enc, const float* __restrict__ x_mark,
                           const float* __restrict__ means, const float* __restrict__ stdev,
                           float* __restrict__ tok)
{
    int i = blockIdx.x * blockDim.x + threadIdx.x;
    if (i >= MROWS * SEQ) return;
    int s = i % SEQ;
    int row = i / SEQ;
    int b = row / LTOK, l = row - b * LTOK;
    float val;
    if (l < NVARS) {
        val = (x_enc[((size_t)b * SEQ + s) * NVARS + l] - means[b * NVARS + l])
              / stdev[b * NVARS + l];
    } else {
        val = x_mark[((size_t)b * SEQ + s) * NMARK + (l - NVARS)];
    }
    tok[i] = val;
}

// ---- causal depthwise conv (width 2) + SiLU; xz is (MROWS x 1024), xi = cols [0,512) ----
__global__ void conv_silu_kernel(const float* __restrict__ xz, float* __restrict__ xc,
                                 const float* __restrict__ cW, const float* __restrict__ cb)
{
    int i = blockIdx.x * blockDim.x + threadIdx.x;
    if (i >= MROWS * DM) return;
    int d = i & (DM - 1);
    int row = i >> 9;
    int t = row % LTOK;
    float cur = xz[(size_t)row * 1024 + d];
    float prev = (t == 0) ? 0.f : xz[(size_t)(row - 1) * 1024 + d];
    float v = prev * cW[d * 2 + 0] + cur * cW[d * 2 + 1] + cb[d];
    xc[i] = v * (1.f / (1.f + __expf(-v)));   // silu
}

// =====================================================================
// Chunked parallel selective scan (3 passes), one-lane-per-channel.
// Lane owns d; h[16] in registers. B/C rows staged to LDS per chunk.
// Summaries layout: [b][c][s][d] (d fastest -> coalesced).
// scan1: aprod = exp(A_s * sum(dt)) computed once at chunk end.
// =====================================================================
__global__ __launch_bounds__(256) void scan1_kernel(
    const float* __restrict__ xc, const float* __restrict__ dt,
    const float* __restrict__ dbc, const float* __restrict__ A_log,
    float* __restrict__ aprod, float* __restrict__ hpart)
{
    __shared__ float Ls[TCH * 32];
    const int tid = threadIdx.x;
    const int d = blockIdx.x * 256 + tid;
    const int c = blockIdx.y;
    const int b = blockIdx.z;
    const int t0 = c * TCH;
    const int tend = min(t0 + TCH, LTOK);
    const size_t rowb = (size_t)b * LTOK;

    for (int i = tid; i < TCH * 32; i += 256) {
        const int tr = min(t0 + (i >> 5), LTOK - 1);
        Ls[i] = dbc[(rowb + tr) * 64 + 32 + (i & 31)];
    }
    __syncthreads();

    float Ads[16];
#pragma unroll
    for (int s = 0; s < 16; ++s) Ads[s] = -__expf(A_log[d * DSTATE + s]);
    float h[16];
#pragma unroll
    for (int s = 0; s < 16; ++s) h[s] = 0.f;
    float sumdt = 0.f;

    for (int t = t0; t < tend; ++t) {
        const size_t row = rowb + t;
        const float dtv = dt[row * DM + d];
        const float xcv = xc[row * DM + d];
        const float du = dtv * xcv;
        sumdt += dtv;
        const float* Bp = &Ls[(t - t0) * 32];
#pragma unroll
        for (int s = 0; s < 16; ++s) {
            const float dA = __expf(dtv * Ads[s]);
            h[s] = dA * h[s] + du * Bp[s];
        }
    }
#pragma unroll
    for (int s = 0; s < 16; ++s) {
        const size_t oidx = ((size_t)(b * CCH + c) * 16 + s) * DM + d;
        aprod[oidx] = __expf(Ads[s] * sumdt);
        hpart[oidx] = h[s];
    }
}

__global__ __launch_bounds__(256) void scan2_kernel(
    const float* __restrict__ aprod, const float* __restrict__ hpart,
    float* __restrict__ hinit)
{
    const int gid = blockIdx.x * 256 + threadIdx.x;   // BATCH*16*DM = 131072
    const int d = gid & (DM - 1);
    const int s = (gid >> 9) & 15;
    const int b = gid >> 13;
    float h = 0.f;
    for (int c = 0; c < CCH; ++c) {
        const size_t idx = ((size_t)(b * CCH + c) * 16 + s) * DM + d;
        const float ap = aprod[idx];
        const float hp = hpart[idx];
        hinit[idx] = h;
        h = hp + ap * h;
    }
}

__global__ __launch_bounds__(256) void scan3_kernel(
    const float* __restrict__ xc, const float* __restrict__ dt,
    const float* __restrict__ dbc, const float* __restrict__ xz,
    const float* __restrict__ A_log, const float* __restrict__ Dp,
    const float* __restrict__ hinit, float* __restrict__ ym)
{
    __shared__ float Ls[TCH * 32];
    const int tid = threadIdx.x;
    const int d = blockIdx.x * 256 + tid;
    const int c = blockIdx.y;
    const int b = blockIdx.z;
    const int t0 = c * TCH;
    const int tend = min(t0 + TCH, LTOK);
    const size_t rowb = (size_t)b * LTOK;

    for (int i = tid; i < TCH * 32; i += 256) {
        const int tr = min(t0 + (i >> 5), LTOK - 1);
        Ls[i] = dbc[(rowb + tr) * 64 + 32 + (i & 31)];
    }
    __syncthreads();

    float Ads[16];
#pragma unroll
    for (int s = 0; s < 16; ++s) Ads[s] = -__expf(A_log[d * DSTATE + s]);
    float h[16];
#pragma unroll
    for (int s = 0; s < 16; ++s)
        h[s] = hinit[((size_t)(b * CCH + c) * 16 + s) * DM + d];
    const float Dd = Dp[d];

    for (int t = t0; t < tend; ++t) {
        const size_t row = rowb + t;
        const float dtv = dt[row * DM + d];
        const float xcv = xc[row * DM + d];
        const float du = dtv * xcv;
        const float* Bp = &Ls[(t - t0) * 32];
        float p0 = 0.f, p1 = 0.f, p2 = 0.f, p3 = 0.f;
#pragma unroll
        for (int s = 0; s < 16; ++s) {
            const float dA = __expf(dtv * Ads[s]);
            const float hn = dA * h[s] + du * Bp[s];
            h[s] = hn;
            const float pc = hn * Bp[16 + s];
            if ((s & 3) == 0) p0 += pc;
            else if ((s & 3) == 1) p1 += pc;
            else if ((s & 3) == 2) p2 += pc;
            else p3 += pc;
        }
        const float y = (p0 + p1) + (p2 + p3) + xcv * Dd;
        const float z = xz[row * 1024 + DM + d];
        ym[row * DM + d] = y * (z * (1.f / (1.f + __expf(-z))));
    }
}

// ---- LayerNorm over DM=512 per row ----
__global__ __launch_bounds__(256) void ln_kernel(const float* __restrict__ in,
                                                 const float* __restrict__ w,
                                                 const float* __restrict__ bp,
                                                 float* __restrict__ out)
{
    const int row = blockIdx.x;
    const int tid = threadIdx.x;
    const float2 v = *(const float2*)(in + (size_t)row * DM + tid * 2);
    float s  = v.x + v.y;
    float ss = v.x * v.x + v.y * v.y;
    for (int off = 32; off; off >>= 1) {
        s  += __shfl_down(s, off);
        ss += __shfl_down(ss, off);
    }
    __shared__ float sh[10];
    const int wid = tid >> 6, lane = tid & 63;
    if (lane == 0) { sh[wid] = s; sh[4 + wid] = ss; }
    __syncthreads();
    if (tid == 0) {
        float S = sh[0] + sh[1] + sh[2] + sh[3];
        float SS = sh[4] + sh[5] + sh[6] + sh[7];
        float mu = S / (float)DM;
        float var = SS / (float)DM - mu * mu;
        sh[8] = mu; sh[9] = rsqrtf(var + EPS_F);
    }
    __syncthreads();
    const float mu = sh[8], rstd = sh[9];
    const int c = tid * 2;
    float2 o;
    o.x = (v.x - mu) * rstd * w[c]     + bp[c];
    o.y = (v.y - mu) * rstd * w[c + 1] + bp[c + 1];
    *(float2*)(out + (size_t)row * DM + c) = o;
}

// =====================================================================
static inline void launch_gemm(hipStream_t st, const float* A, int lda, const float* W,
                               const float* bias, const float* res, float* out, int ldo,
                               int M, int N, int K, int rev, int act,
                               int fin = 0, const float* fstd = nullptr, const float* fmean = nullptr)
{
    dim3 g((N + 127) / 128, (M + 127) / 128);
    hipLaunchKernelGGL(gemm_mfma, g, dim3(256), 0, st,
                       A, lda, W, bias, res, out, ldo, M, N, K, rev, act, fin, fstd, fmean);
}

extern "C" void kernel_launch(void* const* d_in, const int* in_sizes, int n_in,
                              void* d_out, int out_size, void* d_ws, size_t ws_size,
                              hipStream_t stream)
{
    const float* x_enc   = (const float*)d_in[0];
    const float* x_mark  = (const float*)d_in[1];
    const float* emb_W   = (const float*)d_in[4];
    const float* emb_b   = (const float*)d_in[5];
    const float* m_in_W[2]    = { (const float*)d_in[6],  (const float*)d_in[15] };
    const float* m_conv_W[2]  = { (const float*)d_in[7],  (const float*)d_in[16] };
    const float* m_conv_b[2]  = { (const float*)d_in[8],  (const float*)d_in[17] };
    const float* m_xproj_W[2] = { (const float*)d_in[9],  (const float*)d_in[18] };
    const float* m_dt_W[2]    = { (const float*)d_in[10], (const float*)d_in[19] };
    const float* m_dt_b[2]    = { (const float*)d_in[11], (const float*)d_in[20] };
    const float* m_A_log[2]   = { (const float*)d_in[12], (const float*)d_in[21] };
    const float* m_D[2]       = { (const float*)d_in[13], (const float*)d_in[22] };
    const float* m_out_W[2]   = { (const float*)d_in[14], (const float*)d_in[23] };
    const float* conv1_W = (const float*)d_in[24];
    const float* conv1_b = (const float*)d_in[25];
    const float* conv2_W = (const float*)d_in[26];
    const float* conv2_b = (const float*)d_in[27];
    const float* ln1_w = (const float*)d_in[28];
    const float* ln1_b = (const float*)d_in[29];
    const float* ln2_w = (const float*)d_in[30];
    const float* ln2_b = (const float*)d_in[31];
    const float* enc_w = (const float*)d_in[32];
    const float* enc_b = (const float*)d_in[33];
    const float* proj_W = (const float*)d_in[34];
    const float* proj_b = (const float*)d_in[35];

    float* ws = (float*)d_ws;
    size_t o = 0;
    float* means = ws + o; o += 13824;
    float* stdev = ws + o; o += 13824;
    float* xbuf  = ws + o; o += (size_t)MROWS * DM;
    float* accb  = ws + o; o += (size_t)MROWS * DM;
    float* xzb   = ws + o; o += (size_t)MROWS * 1024;
    float* xcb   = ws + o; o += (size_t)MROWS * DM;
    float* dtb   = ws + o; o += (size_t)MROWS * DM;
    float* dbcb  = ws + o; o += (size_t)MROWS * 64;
    float* ybuf  = ws + o; o += (size_t)MROWS * DM;
    const size_t NSUM = (size_t)BATCH * CCH * 16 * DM;   // 4,194,304
    float* aprod = ws + o; o += NSUM;
    float* hpart = ws + o; o += NSUM;
    float* hinit = ws + o; o += NSUM;
    float* tok   = xzb;          // MROWS x 96, only used before layer 0
    float* hbuf  = xzb;          // ffn hidden, only used after xz dead
    float* x2buf = ybuf;         // LN1 output, only used after y dead

    // 1) normalization stats + token matrix + embedding
    hipLaunchKernelGGL(stats_kernel, dim3((BATCH * NVARS + 255) / 256), dim3(256), 0, stream,
                       x_enc, means, stdev);
    hipLaunchKernelGGL(tok_kernel, dim3((MROWS * SEQ + 255) / 256), dim3(256), 0, stream,
                       x_enc, x_mark, means, stdev, tok);
    launch_gemm(stream, tok, SEQ, emb_W, emb_b, nullptr, xbuf, DM, MROWS, DM, SEQ, 0, 0);

    // 2) encoder layers
    for (int l = 0; l < 2; ++l) {
        for (int dir = 0; dir < 2; ++dir) {   // 0 = fwd (mf), 1 = rev (mr)
            const float* inW  = m_in_W[dir]    + (size_t)l * 2 * DM * DM;
            const float* cW   = m_conv_W[dir]  + (size_t)l * DM * 2;
            const float* cb   = m_conv_b[dir]  + (size_t)l * DM;
            const float* xpW  = m_xproj_W[dir] + (size_t)l * 64 * DM;
            const float* dtW  = m_dt_W[dir]    + (size_t)l * DM * DTRANK;
            const float* dtbias = m_dt_b[dir]  + (size_t)l * DM;
            const float* Alog = m_A_log[dir]   + (size_t)l * DM * DSTATE;
            const float* Dp   = m_D[dir]       + (size_t)l * DM;
            const float* outW = m_out_W[dir]   + (size_t)l * DM * DM;

            // xz = x(rev?) @ in_W.T   (M x 1024)
            launch_gemm(stream, xbuf, DM, inW, nullptr, nullptr, xzb, 1024,
                        MROWS, 2 * DM, DM, dir, 0);
            // xc = silu(causal_conv(xi))
            hipLaunchKernelGGL(conv_silu_kernel, dim3((MROWS * DM + 255) / 256), dim3(256),
                               0, stream, xzb, xcb, cW, cb);
            // dbc = xc @ xproj_W.T   (M x 64)
            launch_gemm(stream, xcb, DM, xpW, nullptr, nullptr, dbcb, 64,
                        MROWS, 64, DM, 0, 0);
            // dt = softplus(dtr @ dt_W.T + dt_b)   (M x 512)
            launch_gemm(stream, dbcb, 64, dtW, dtbias, nullptr, dtb, DM,
                        MROWS, DM, DTRANK, 0, 2);
            // selective scan: 3-pass chunked parallel scan
            hipLaunchKernelGGL(scan1_kernel, dim3(2, CCH, BATCH), dim3(256), 0, stream,
                               xcb, dtb, dbcb, Alog, aprod, hpart);
            hipLaunchKernelGGL(scan2_kernel, dim3((BATCH * 16 * DM) / 256), dim3(256), 0, stream,
                               aprod, hpart, hinit);
            hipLaunchKernelGGL(scan3_kernel, dim3(2, CCH, BATCH), dim3(256), 0, stream,
                               xcb, dtb, dbcb, xzb, Alog, Dp, hinit, ybuf);
            // acc = (dir==0 ? x : acc) + ym(rev?) @ out_W.T
            launch_gemm(stream, ybuf, DM, outW, nullptr, dir == 0 ? xbuf : accb,
                        accb, DM, MROWS, DM, DM, dir, 0);
        }
        // x2 = LN1(acc)
        hipLaunchKernelGGL(ln_kernel, dim3(MROWS), dim3(256), 0, stream,
                           accb, ln1_w + l * DM, ln1_b + l * DM, x2buf);
        // h = relu(x2 @ conv1_W.T + b1)
        launch_gemm(stream, x2buf, DM, conv1_W + (size_t)l * DFF * DM,
                    conv1_b + l * DFF, nullptr, hbuf, DFF, MROWS, DFF, DM, 0, 1);
        // acc = x2 + h @ conv2_W.T + b2
        launch_gemm(stream, hbuf, DFF, conv2_W + (size_t)l * DM * DFF,
                    conv2_b + l * DM, x2buf, accb, DM, MROWS, DM, DFF, 0, 0);
        // x = LN2(acc)
        hipLaunchKernelGGL(ln_kernel, dim3(MROWS), dim3(256), 0, stream,
                           accb, ln2_w + l * DM, ln2_b + l * DM, xbuf);
    }

    // 3) final norm + projection + de-norm (transposed write into d_out)
    hipLaunchKernelGGL(ln_kernel, dim3(MROWS), dim3(256), 0, stream,
                       xbuf, enc_w, enc_b, x2buf);
    launch_gemm(stream, x2buf, DM, proj_W, proj_b, nullptr, (float*)d_out, 0,
                MROWS, PRED, DM, 0, 0, 1, stdev, means);
}